// Round 4
// baseline (298.579 us; speedup 1.0000x reference)
//
#include <hip/hip_runtime.h>

typedef __attribute__((ext_vector_type(4))) float    float4v;
typedef __attribute__((ext_vector_type(4))) _Float16 half4v;

// Problem geometry (fixed by reference setup_inputs).
constexpr int B_ = 8;
constexpr int H_ = 480;
constexpr int W_ = 640;
constexpr int HW = H_ * W_;          // 307200
constexpr int N  = B_ * HW;          // 2457600 pixels

// ---------------------------------------------------------------------------
// Weight precompute, vectorized 4 px/thread.
// One (b, d) slice per blockIdx.y (24 slices): 9 guided-plane float4 read
// streams + 1 fuse read + 9 half4 weight write streams per block.
// w[plane][p], plane = d*9+c, p = b*HW + hw.
// ---------------------------------------------------------------------------
__global__ __launch_bounds__(256) void wprep_kernel(
    const float* __restrict__ g1, const float* __restrict__ g2,
    const float* __restrict__ g3, const float* __restrict__ fuse,
    _Float16* __restrict__ w)
{
    const int q  = blockIdx.x * 256 + threadIdx.x;   // quad index in slice, < HW/4
    const int z  = blockIdx.y;                       // b*3 + d
    const int b  = z / 3;
    const int d  = z - b * 3;
    const int hw = q * 4;
    const size_t p = (size_t)b * HW + hw;

    const float* gs[3] = {g1, g2, g3};
    const float* gb = gs[d] + (size_t)b * 9 * HW + hw;

    float4v e[9];
    float4v m = {-1e30f, -1e30f, -1e30f, -1e30f};
#pragma unroll
    for (int c = 0; c < 9; ++c) {
        e[c] = *(const float4v*)(gb + (size_t)c * HW);
#pragma unroll
        for (int k = 0; k < 4; ++k) m[k] = fmaxf(m[k], e[c][k]);
    }
    float4v s = {0.f, 0.f, 0.f, 0.f};
#pragma unroll
    for (int c = 0; c < 9; ++c)
#pragma unroll
        for (int k = 0; k < 4; ++k) { e[c][k] = __expf(e[c][k] - m[k]); s[k] += e[c][k]; }

    float4v f = *(const float4v*)(fuse + ((size_t)b * 3 + d) * HW + hw);
#pragma unroll
    for (int k = 0; k < 4; ++k) f[k] /= s[k];

#pragma unroll
    for (int c = 0; c < 9; ++c) {
        half4v hv;
#pragma unroll
        for (int k = 0; k < 4; ++k) hv[k] = (_Float16)(e[c][k] * f[k]);
        *(half4v*)(w + (size_t)(d * 9 + c) * N + p) = hv;
    }
}

// ---------------------------------------------------------------------------
// One propagation step: out[p] = sum of 27 taps x * w (fp16 weights).
// 1 pixel/thread; a wave covers 64 consecutive j -> all loads coalesced.
// ---------------------------------------------------------------------------
__global__ __launch_bounds__(256) void prop_kernel(
    const float* __restrict__ xin, const _Float16* __restrict__ w,
    float* __restrict__ xout)
{
    const int j  = blockIdx.x * 64 + (threadIdx.x & 63);
    const int i  = blockIdx.y * 4  + (threadIdx.x >> 6);
    const int b  = blockIdx.z;
    const int hw = i * W_ + j;
    const int p  = b * HW + hw;

    const float* xb = xin + (size_t)b * HW;
    float acc = 0.f;
#pragma unroll
    for (int d = 1; d <= 3; ++d) {
#pragma unroll
        for (int ki = 0; ki < 3; ++ki) {
            const int ii = i + (ki - 1) * d;
            const bool vi = (unsigned)ii < (unsigned)H_;
#pragma unroll
            for (int kj = 0; kj < 3; ++kj) {
                const int jj = j + (kj - 1) * d;
                float xv = 0.f;
                if (vi && (unsigned)jj < (unsigned)W_)
                    xv = xb[ii * W_ + jj];
                const int plane = (d - 1) * 9 + ki * 3 + kj;
                acc = fmaf(xv, (float)w[(size_t)plane * N + p], acc);
            }
        }
    }
    xout[p] = acc;
}

// ---------------------------------------------------------------------------
extern "C" void kernel_launch(void* const* d_in, const int* in_sizes, int n_in,
                              void* d_out, int out_size, void* d_ws, size_t ws_size,
                              hipStream_t stream)
{
    const float* g1   = (const float*)d_in[0];
    const float* g2   = (const float*)d_in[1];
    const float* g3   = (const float*)d_in[2];
    const float* fuse = (const float*)d_in[3];
    const float* x    = (const float*)d_in[4];
    float* out = (float*)d_out;

    char* ws = (char*)d_ws;
    _Float16* w = (_Float16*)ws;                    // 27*N*2 = 132.7 MB
    float* xa = (float*)(ws + (size_t)27 * N * 2);  // ping
    float* xb = xa + N;                             // pong

    // wprep: HW/4 quads per slice, 24 slices.
    wprep_kernel<<<dim3(HW / 4 / 256, B_ * 3), 256, 0, stream>>>(g1, g2, g3, fuse, w);

    const dim3 pgrid(W_ / 64, H_ / 4, B_);
    const float* src = x;
    float* bufs[2] = {xa, xb};
    for (int t = 0; t < 8; ++t) {
        float* dst = (t == 7) ? out : bufs[t & 1];
        prop_kernel<<<pgrid, 256, 0, stream>>>(src, w, dst);
        src = dst;
    }
}